// Round 4
// baseline (372.291 us; speedup 1.0000x reference)
//
#include <hip/hip_runtime.h>
#include <hip/hip_bf16.h>
#include <math.h>

// Problem: B=131072, D=512, C=5, K=10 experts.
// GEMM [B,512] x [512,64pad] bf16 MFMA + per-row softmax/relu epilogue.
// R4: 32 rows/wave (2 row-tiles), depth-2 register prefetch pipeline,
// full K unroll. B fragments in LDS (64 KB), staged once per block.
#define BATCH   131072
#define DIM     512
#define NCLS    5
#define NEXP    10
#define NW      60
#define NCOL    64
#define PACK_TPB 256
#define TPB     512            // 8 waves
#define ROWS_PER_WAVE 32       // 2 row-tiles of 16
#define ROWS_PER_BLOCK 256     // 8 waves * 32 rows
#define NCHUNK  16             // 512 / 32
#define EPS_STRIDE 65          // (tid*65+k)%32 = (tid+k)%32 -> conflict-free reads

typedef short bf16x8 __attribute__((ext_vector_type(8)));
typedef float f32x4  __attribute__((ext_vector_type(4)));

// ---------------------------------------------------------------------------
// Pack weights into per-lane B-fragment order for mfma_f32_16x16x32_bf16:
// wfrag[((c*4+t)*64+lane)*8+j] = B[k=32c+(lane>>4)*8+j][n=16t+(lane&15)]
// n<10: Wg col n; 10<=n<60: We[(n-10)/5][d][(n-10)%5]; else 0. bpack: biases.
// ---------------------------------------------------------------------------
__global__ void pack_w_kernel(const float* __restrict__ We,
                              const float* __restrict__ be,
                              const float* __restrict__ Wg,
                              const float* __restrict__ bg,
                              unsigned short* __restrict__ wfrag,
                              float* __restrict__ bpack) {
    int idx = blockIdx.x * PACK_TPB + threadIdx.x;   // 0 .. 32767
    int c    = idx >> 11;
    int t    = (idx >> 9) & 3;
    int lane = (idx >> 3) & 63;
    int j    = idx & 7;
    int d = c * 32 + (lane >> 4) * 8 + j;
    int n = t * 16 + (lane & 15);
    float v = 0.0f;
    if (n < NEXP) {
        v = Wg[d * NEXP + n];
    } else if (n < NW) {
        int k  = (n - NEXP) / NCLS;
        int cc = (n - NEXP) % NCLS;
        v = We[(k * DIM + d) * NCLS + cc];
    }
    wfrag[idx] = __builtin_bit_cast(unsigned short, __float2bfloat16(v));
    if (idx < NCOL) {
        float bv = 0.0f;
        if (idx < NEXP) bv = bg[idx];
        else if (idx < NW) {
            int k  = (idx - NEXP) / NCLS;
            int cc = (idx - NEXP) % NCLS;
            bv = be[k * NCLS + cc];
        }
        bpack[idx] = bv;
    }
}

static __device__ __forceinline__ bf16x8 cvt8(float4 x, float4 y) {
    bf16x8 o;
    o[0] = (short)__builtin_bit_cast(unsigned short, __float2bfloat16(x.x));
    o[1] = (short)__builtin_bit_cast(unsigned short, __float2bfloat16(x.y));
    o[2] = (short)__builtin_bit_cast(unsigned short, __float2bfloat16(x.z));
    o[3] = (short)__builtin_bit_cast(unsigned short, __float2bfloat16(x.w));
    o[4] = (short)__builtin_bit_cast(unsigned short, __float2bfloat16(y.x));
    o[5] = (short)__builtin_bit_cast(unsigned short, __float2bfloat16(y.y));
    o[6] = (short)__builtin_bit_cast(unsigned short, __float2bfloat16(y.z));
    o[7] = (short)__builtin_bit_cast(unsigned short, __float2bfloat16(y.w));
    return o;
}

// ---------------------------------------------------------------------------
// Main kernel. 8 waves, each owns 32 rows x 64 cols (2 row-tiles x 4 col-tiles,
// 8 accumulators). K-loop fully unrolled, depth-2 register prefetch: chunk c
// computes on registers loaded at c-2 -> 8 KB/wave always in flight.
// ---------------------------------------------------------------------------
__global__ __launch_bounds__(TPB) void moe_mfma_kernel(
        const float* __restrict__ emb,
        const float4* __restrict__ wfrag4,
        const float* __restrict__ bpack,
        float* __restrict__ out) {
    // union: B fragments (4096 float4 = 64 KB) / epilogue 256 x 65 f = 66.6 KB
    __shared__ float4 smem4[4160];

    const int tid = threadIdx.x;

    // ---- stage B once: 64 KB coalesced ----
    #pragma unroll
    for (int i = 0; i < 8; ++i)
        smem4[i * TPB + tid] = wfrag4[i * TPB + tid];
    __syncthreads();

    const int w = tid >> 6;
    const int L = tid & 63;
    const int r = L & 15;
    const int q = L >> 4;

    const size_t wrb = (size_t)blockIdx.x * ROWS_PER_BLOCK + w * ROWS_PER_WAVE;
    const float* a0p = emb + (wrb + r) * DIM + q * 8;          // row-tile 0
    const float* a1p = a0p + 16 * DIM;                          // row-tile 1
    const bf16x8* bl = reinterpret_cast<const bf16x8*>(smem4);

    f32x4 acc[2][4];
    #pragma unroll
    for (int t2 = 0; t2 < 2; ++t2)
        #pragma unroll
        for (int ct = 0; ct < 4; ++ct)
            acc[t2][ct] = (f32x4){0.f, 0.f, 0.f, 0.f};

    // depth-2 prefetch registers: pa[slot][tile*2 + half]
    float4 pa[2][4];
    #pragma unroll
    for (int s = 0; s < 2; ++s) {
        pa[s][0] = *reinterpret_cast<const float4*>(a0p + s * 32);
        pa[s][1] = *reinterpret_cast<const float4*>(a0p + s * 32 + 4);
        pa[s][2] = *reinterpret_cast<const float4*>(a1p + s * 32);
        pa[s][3] = *reinterpret_cast<const float4*>(a1p + s * 32 + 4);
    }

    #pragma unroll
    for (int c = 0; c < NCHUNK; ++c) {
        const int s = c & 1;
        // consume current chunk's A into bf16 fragments
        bf16x8 af0 = cvt8(pa[s][0], pa[s][1]);
        bf16x8 af1 = cvt8(pa[s][2], pa[s][3]);
        // prefetch chunk c+2 into the freed slot
        if (c < NCHUNK - 2) {
            pa[s][0] = *reinterpret_cast<const float4*>(a0p + (c + 2) * 32);
            pa[s][1] = *reinterpret_cast<const float4*>(a0p + (c + 2) * 32 + 4);
            pa[s][2] = *reinterpret_cast<const float4*>(a1p + (c + 2) * 32);
            pa[s][3] = *reinterpret_cast<const float4*>(a1p + (c + 2) * 32 + 4);
        }
        // B fragments from LDS (shared by both row-tiles), immediate offsets
        bf16x8 b0 = bl[(c * 4 + 0) * 64 + L];
        bf16x8 b1 = bl[(c * 4 + 1) * 64 + L];
        bf16x8 b2 = bl[(c * 4 + 2) * 64 + L];
        bf16x8 b3 = bl[(c * 4 + 3) * 64 + L];
        acc[0][0] = __builtin_amdgcn_mfma_f32_16x16x32_bf16(af0, b0, acc[0][0], 0, 0, 0);
        acc[0][1] = __builtin_amdgcn_mfma_f32_16x16x32_bf16(af0, b1, acc[0][1], 0, 0, 0);
        acc[0][2] = __builtin_amdgcn_mfma_f32_16x16x32_bf16(af0, b2, acc[0][2], 0, 0, 0);
        acc[0][3] = __builtin_amdgcn_mfma_f32_16x16x32_bf16(af0, b3, acc[0][3], 0, 0, 0);
        acc[1][0] = __builtin_amdgcn_mfma_f32_16x16x32_bf16(af1, b0, acc[1][0], 0, 0, 0);
        acc[1][1] = __builtin_amdgcn_mfma_f32_16x16x32_bf16(af1, b1, acc[1][1], 0, 0, 0);
        acc[1][2] = __builtin_amdgcn_mfma_f32_16x16x32_bf16(af1, b2, acc[1][2], 0, 0, 0);
        acc[1][3] = __builtin_amdgcn_mfma_f32_16x16x32_bf16(af1, b3, acc[1][3], 0, 0, 0);
    }

    // ---- epilogue: reuse LDS for C transpose ----
    __syncthreads();                   // all waves done with B
    float* eps = reinterpret_cast<float*>(smem4);   // 256 x 65 floats
    // C/D layout: col = lane&15, row = quad*4 + reg
    #pragma unroll
    for (int t2 = 0; t2 < 2; ++t2) {
        #pragma unroll
        for (int i = 0; i < 4; ++i) {
            int rowl = w * ROWS_PER_WAVE + t2 * 16 + q * 4 + i;
            eps[rowl * EPS_STRIDE +  0 + r] = acc[t2][0][i];
            eps[rowl * EPS_STRIDE + 16 + r] = acc[t2][1][i];
            eps[rowl * EPS_STRIDE + 32 + r] = acc[t2][2][i];
            eps[rowl * EPS_STRIDE + 48 + r] = acc[t2][3][i];
        }
    }
    __syncthreads();

    // one thread per row: softmax(10) + relu + gate-weighted sum -> 5 outputs
    if (tid < ROWS_PER_BLOCK) {
        const float* row = eps + tid * EPS_STRIDE;
        float g[NEXP];
        float m = -INFINITY;
        #pragma unroll
        for (int k = 0; k < NEXP; ++k) {
            g[k] = row[k] + bpack[k];
            m = fmaxf(m, g[k]);
        }
        float s = 0.0f;
        #pragma unroll
        for (int k = 0; k < NEXP; ++k) {
            g[k] = __expf(g[k] - m);
            s += g[k];
        }
        float inv = 1.0f / s;

        float o[NCLS] = {0.f, 0.f, 0.f, 0.f, 0.f};
        #pragma unroll
        for (int k = 0; k < NEXP; ++k) {
            float gk = g[k] * inv;
            #pragma unroll
            for (int cc = 0; cc < NCLS; ++cc) {
                int n = NEXP + k * NCLS + cc;
                float e = row[n] + bpack[n];
                e = fmaxf(e, 0.0f);
                o[cc] = fmaf(gk, e, o[cc]);
            }
        }
        size_t ob = ((size_t)blockIdx.x * ROWS_PER_BLOCK + tid) * NCLS;
        #pragma unroll
        for (int cc = 0; cc < NCLS; ++cc) out[ob + cc] = o[cc];
    }
}

extern "C" void kernel_launch(void* const* d_in, const int* in_sizes, int n_in,
                              void* d_out, int out_size, void* d_ws, size_t ws_size,
                              hipStream_t stream) {
    const float* emb = (const float*)d_in[0];
    const float* We  = (const float*)d_in[1];
    const float* be  = (const float*)d_in[2];
    const float* Wg  = (const float*)d_in[3];
    const float* bg  = (const float*)d_in[4];
    float* out = (float*)d_out;

    unsigned short* wfrag = (unsigned short*)d_ws;            // 64 KB
    float* bpack = (float*)((char*)d_ws + 32768 * sizeof(unsigned short));

    pack_w_kernel<<<(16 * 4 * 64 * 8) / PACK_TPB, PACK_TPB, 0, stream>>>(
        We, be, Wg, bg, wfrag, bpack);
    moe_mfma_kernel<<<BATCH / ROWS_PER_BLOCK, TPB, 0, stream>>>(
        emb, (const float4*)wfrag, bpack, out);
}